// Round 1
// baseline (123.856 us; speedup 1.0000x reference)
//
#include <hip/hip_runtime.h>
#include <hip/hip_bf16.h>

// Problem constants (B,C,N fixed by the reference)
#define B_ 32
#define C_ 64
#define N_ 16384
#define NCH 16              // chunks per batch in pass 1
#define NC (N_/NCH)         // 1024 columns per block
#define TT 64               // tile columns
#define NT (NC/TT)          // 16 tiles per block
constexpr float BN_INV = 1.0f / (32.0f * 16384.0f);   // 1/(B*N)

typedef float f32x4 __attribute__((ext_vector_type(4)));
typedef short s16x8 __attribute__((ext_vector_type(8)));

// ---- workspace layout (float offsets) ----
constexpr size_t WS_GPART = 0;                               // [512][4096] per-(b,chunk) Gram partials
constexpr size_t WS_RPART = WS_GPART + (size_t)512 * 4096;   // [512][64]   rowsum partials
constexpr size_t WS_G     = WS_RPART + (size_t)512 * 64;     // [32][4096]  per-batch Gram
constexpr size_t WS_RB    = WS_G + (size_t)32 * 4096;        // [32][64]    per-batch rowsums
constexpr size_t WS_V     = WS_RB + (size_t)32 * 64;         // [32][16384] channel means
constexpr size_t WS_GBAR  = WS_V + (size_t)32 * 16384;       // [4096]      E[x x^T]
constexpr size_t WS_M     = WS_GBAR + 4096;                  // [64]        E[x]
constexpr size_t WS_A     = WS_M + 64;                       // [4096]      A = Wq2 diag(D) Wq
constexpr size_t WS_AVEC  = WS_A + 4096;                     // [64]        a vector
constexpr size_t WS_W     = WS_AVEC + 64;                    // [32][64]    w_b = Wc @ attnmax
// total ~11.2 MB of d_ws

__device__ constexpr int P1I[10] = {0,0,0,0,1,1,1,2,2,3};
__device__ constexpr int P1J[10] = {0,1,2,3,1,2,3,2,3,3};

__device__ __forceinline__ unsigned short bf16_rne(float f, float& hf) {
    unsigned u = __float_as_uint(f);
    unsigned r = u + 0x7FFFu + ((u >> 16) & 1u);
    hf = __uint_as_float(r & 0xFFFF0000u);
    return (unsigned short)(r >> 16);
}
__device__ __forceinline__ unsigned short bf16_rne_s(float f) {
    unsigned u = __float_as_uint(f);
    unsigned r = u + 0x7FFFu + ((u >> 16) & 1u);
    return (unsigned short)(r >> 16);
}

// ============ K1: read x once -> Gram partials (hi/lo bf16 MFMA), rowsums, v ============
__global__ __launch_bounds__(256, 2) void k1(const float* __restrict__ x, float* __restrict__ ws) {
    // smem map (bytes): [0,36864) hi/lo tiles (2 bufs), [36864,45056) vbuf (2 bufs),
    //                   [45056,49408) rbuf.  Psum[64][65] aliases [0,16640) after main loop.
    __shared__ __align__(16) unsigned char smem[49408];

    const int t    = threadIdx.x;
    const int wv   = t >> 6;         // wave 0..3
    const int lane = t & 63;
    const int b  = blockIdx.x >> 4;
    const int ch = blockIdx.x & 15;
    const float* xb = x + (size_t)b * C_ * N_ + (size_t)ch * NC;
    const int lr  = t >> 4;          // 0..15 row-group for loads
    const int lc4 = (t & 15) * 4;    // column quad

    f32x4 accP1[10], accP2[16];
    #pragma unroll
    for (int i = 0; i < 10; ++i) accP1[i] = (f32x4){0.f,0.f,0.f,0.f};
    #pragma unroll
    for (int i = 0; i < 16; ++i) accP2[i] = (f32x4){0.f,0.f,0.f,0.f};
    float rs[4] = {0.f, 0.f, 0.f, 0.f};

    float4 ld[4];
    #pragma unroll
    for (int p = 0; p < 4; ++p)
        ld[p] = *(const float4*)(xb + (size_t)(p * 16 + lr) * N_ + lc4);

    for (int tt = 0; tt < NT; ++tt) {
        const int buf = tt & 1;
        unsigned short* hiT = (unsigned short*)(smem + buf * 18432);
        unsigned short* loT = hiT + 4608;
        float* vbuf = (float*)(smem + 36864 + buf * 4096);

        // convert regs -> bf16 hi/lo tiles; accumulate v (col) and r (row) partials
        float4 vp = {0.f, 0.f, 0.f, 0.f};
        #pragma unroll
        for (int p = 0; p < 4; ++p) {
            const float x0 = ld[p].x, x1 = ld[p].y, x2 = ld[p].z, x3 = ld[p].w;
            float h0f, h1f, h2f, h3f;
            unsigned short h0 = bf16_rne(x0, h0f), h1 = bf16_rne(x1, h1f);
            unsigned short h2 = bf16_rne(x2, h2f), h3 = bf16_rne(x3, h3f);
            unsigned short l0 = bf16_rne_s(x0 - h0f), l1 = bf16_rne_s(x1 - h1f);
            unsigned short l2 = bf16_rne_s(x2 - h2f), l3 = bf16_rne_s(x3 - h3f);
            const int row = p * 16 + lr;
            ushort4 hv; hv.x = h0; hv.y = h1; hv.z = h2; hv.w = h3;
            ushort4 lv; lv.x = l0; lv.y = l1; lv.z = l2; lv.w = l3;
            *((ushort4*)(hiT + row * 72 + lc4)) = hv;
            *((ushort4*)(loT + row * 72 + lc4)) = lv;
            vp.x += x0; vp.y += x1; vp.z += x2; vp.w += x3;
            rs[p] += x0 + x1 + x2 + x3;
        }
        *((float4*)(vbuf + lr * 64 + lc4)) = vp;
        __syncthreads();   // publish tile tt; also fences compute of tile tt-1 (other buffer)

        if (tt + 1 < NT) {
            #pragma unroll
            for (int p = 0; p < 4; ++p)
                ld[p] = *(const float4*)(xb + (size_t)(p * 16 + lr) * N_ + (size_t)(tt + 1) * TT + lc4);
        }

        if ((tt & 3) == wv) {   // this wave owns tile tt
            // v: sum 64 channels per column
            float s = 0.f;
            #pragma unroll
            for (int g = 0; g < 16; ++g) s += vbuf[g * 64 + lane];
            ws[WS_V + (size_t)b * N_ + (size_t)ch * NC + tt * TT + lane] = s * 0.015625f;

            // Gram: P1 = Hi Hi^T (upper blocks), P2 = Hi Lo^T (all blocks)
            #pragma unroll
            for (int sl = 0; sl < 2; ++sl) {
                const int kc = sl * 32 + 8 * (lane >> 4);
                const int rr = lane & 15;
                s16x8 hf[4], lf[4];
                #pragma unroll
                for (int g = 0; g < 4; ++g) {
                    hf[g] = *((const s16x8*)(hiT + (16 * g + rr) * 72 + kc));
                    lf[g] = *((const s16x8*)(loT + (16 * g + rr) * 72 + kc));
                }
                #pragma unroll
                for (int i = 0; i < 10; ++i)
                    accP1[i] = __builtin_amdgcn_mfma_f32_16x16x32_bf16(hf[P1I[i]], hf[P1J[i]], accP1[i], 0, 0, 0);
                #pragma unroll
                for (int i = 0; i < 16; ++i)
                    accP2[i] = __builtin_amdgcn_mfma_f32_16x16x32_bf16(hf[i >> 2], lf[i & 3], accP2[i], 0, 0, 0);
            }
        }
    }

    // rowsum partials -> global
    float* rbuf = (float*)(smem + 45056);        // [64][17]
    #pragma unroll
    for (int p = 0; p < 4; ++p) rbuf[(p * 16 + lr) * 17 + (t & 15)] = rs[p];
    __syncthreads();                              // also fences last tile's compute
    if (t < 64) {
        float s = 0.f;
        #pragma unroll
        for (int g = 0; g < 16; ++g) s += rbuf[t * 17 + g];
        ws[WS_RPART + (size_t)blockIdx.x * 64 + t] = s;
    }

    // assemble G = P1(sym) + P2 + P2^T in LDS (aliases tile buffers; safe after barrier above)
    float* Ps = (float*)smem;                     // [64][65]
    for (int e = t; e < 64 * 65; e += 256) Ps[e] = 0.f;
    __syncthreads();
    const int r0 = 4 * (lane >> 4), cc = lane & 15;
    for (int w = 0; w < 4; ++w) {
        if (wv == w) {
            #pragma unroll
            for (int i = 0; i < 10; ++i) {
                const int bi = P1I[i], bj = P1J[i];
                #pragma unroll
                for (int j = 0; j < 4; ++j) {
                    const float v = accP1[i][j];
                    Ps[(16 * bi + r0 + j) * 65 + 16 * bj + cc] += v;
                    if (bi != bj) Ps[(16 * bj + cc) * 65 + 16 * bi + r0 + j] += v;
                }
            }
            #pragma unroll
            for (int i = 0; i < 16; ++i) {
                const int bi = i >> 2, bj = i & 3;
                #pragma unroll
                for (int j = 0; j < 4; ++j) {
                    const float v = accP2[i][j];
                    Ps[(16 * bi + r0 + j) * 65 + 16 * bj + cc] += v;
                    Ps[(16 * bj + cc) * 65 + 16 * bi + r0 + j] += v;
                }
            }
        }
        __syncthreads();
    }
    float* gp = ws + WS_GPART + (size_t)blockIdx.x * 4096;
    for (int e = t; e < 4096; e += 256) gp[e] = Ps[(e >> 6) * 65 + (e & 63)];
}

// ============ K2a: reduce chunk partials -> per-batch G, r ============
__global__ __launch_bounds__(256) void k2a(float* __restrict__ ws) {
    const int b = blockIdx.x >> 3, sl = blockIdx.x & 7, t = threadIdx.x;
    #pragma unroll
    for (int h = 0; h < 2; ++h) {
        const int e = sl * 512 + h * 256 + t;
        float s = 0.f;
        for (int chn = 0; chn < 16; ++chn) s += ws[WS_GPART + ((size_t)(b * 16 + chn)) * 4096 + e];
        ws[WS_G + (size_t)b * 4096 + e] = s;
    }
    if (sl == 0 && t < 64) {
        float s = 0.f;
        for (int chn = 0; chn < 16; ++chn) s += ws[WS_RPART + (size_t)(b * 16 + chn) * 64 + t];
        ws[WS_RB + b * 64 + t] = s;
    }
}

// ============ K2b1: Gbar = E[x x^T], m = E[x] ============
__global__ __launch_bounds__(64) void k2b1(float* __restrict__ ws) {
    const int e = blockIdx.x * 64 + threadIdx.x;
    float s = 0.f;
    for (int b = 0; b < 32; ++b) s += ws[WS_G + (size_t)b * 4096 + e];
    ws[WS_GBAR + e] = s * BN_INV;
    if (blockIdx.x == 0) {
        const int c = threadIdx.x;
        float sm = 0.f;
        for (int b = 0; b < 32; ++b) sm += ws[WS_RB + b * 64 + c];
        ws[WS_M + c] = sm * BN_INV;
    }
}

// ============ K2b2: BN stats -> A = Wq2 diag(D) Wq, a vector ============
__global__ __launch_bounds__(256) void k2b2(const float* __restrict__ Wq, const float* __restrict__ bq,
                                            const float* __restrict__ gamma, const float* __restrict__ beta,
                                            const float* __restrict__ Wq2, const float* __restrict__ bq2,
                                            float* __restrict__ ws) {
    __shared__ float Gb[64 * 65], Wl[64 * 65], W2[64 * 65];
    __shared__ float mS[64], muS[64], DS[64], ab[64], qp[4][64];
    const int t = threadIdx.x;
    for (int e = t; e < 4096; e += 256) {
        const int r = e >> 6, c = e & 63;
        Gb[r * 65 + c] = ws[WS_GBAR + e];
        Wl[r * 65 + c] = Wq[e];
        W2[r * 65 + c] = Wq2[e];
    }
    if (t < 64) mS[t] = ws[WS_M + t];
    __syncthreads();
    if (t < 64) {
        float s = 0.f;
        for (int c = 0; c < 64; ++c) s += Wl[t * 65 + c] * mS[c];
        muS[t] = s;                                     // mu0 (bias-free part of mu)
    }
    __syncthreads();
    {   // quad_o = Wq_o^T Gbar Wq_o, split over 4 d-quarters (one per wave)
        const int o = t & 63, q = t >> 6;
        float s = 0.f;
        for (int dd = 0; dd < 16; ++dd) {
            const int d = q * 16 + dd;
            float inner = 0.f;
            for (int c = 0; c < 64; ++c) inner += Gb[c * 65 + d] * Wl[o * 65 + c];
            s += Wl[o * 65 + d] * inner;
        }
        qp[q][o] = s;
    }
    __syncthreads();
    if (t < 64) {
        const float quad = qp[0][t] + qp[1][t] + qp[2][t] + qp[3][t];
        const float mu0 = muS[t];
        const float var = quad - mu0 * mu0;             // bq cancels exactly
        const float D = gamma[t] * rsqrtf(var + 1e-5f);
        DS[t] = D;
        ab[t] = beta[t] - D * mu0;                      // D*(bq-mu)+beta with mu = mu0+bq
    }
    __syncthreads();
    for (int e = t; e < 4096; e += 256) {               // Gb := diag(D) Wq (Gbar now dead)
        const int k = e >> 6, c = e & 63;
        Gb[k * 65 + c] = DS[k] * Wl[k * 65 + c];
    }
    __syncthreads();
    {
        const int o = t >> 2, c0 = (t & 3) * 16;
        for (int ci = 0; ci < 16; ++ci) {
            const int c = c0 + ci;
            float s = 0.f;
            for (int k = 0; k < 64; ++k) s += W2[o * 65 + k] * Gb[k * 65 + c];
            ws[WS_A + o * 64 + c] = s;
        }
    }
    if (t < 64) {
        float s = 0.f;
        for (int k = 0; k < 64; ++k) s += W2[t * 65 + k] * ab[k];
        ws[WS_AVEC + t] = s + bq2[t];
    }
}

// ============ K2c: per-batch attn = A G S^T + rank-1 terms, rowmax, w = Wc @ max ============
__global__ __launch_bounds__(256) void k2c(const float* __restrict__ Wsr, const float* __restrict__ bsr,
                                           const float* __restrict__ Wc, float* __restrict__ ws) {
    __shared__ float Al[64 * 65], Gl[64 * 65], Sl[64 * 65];
    __shared__ float rl[64], ul[64], pl[64], av[64], sb[64], aml[64];
    __shared__ float pm[64][4];
    const int b = blockIdx.x, t = threadIdx.x;
    for (int e = t; e < 4096; e += 256) {
        const int r = e >> 6, c = e & 63;
        Al[r * 65 + c] = ws[WS_A + e];
        Gl[r * 65 + c] = ws[WS_G + (size_t)b * 4096 + e];
        Sl[r * 65 + c] = Wsr[e];
    }
    if (t < 64) { rl[t] = ws[WS_RB + b * 64 + t]; av[t] = ws[WS_AVEC + t]; sb[t] = bsr[t]; }
    __syncthreads();
    if (t < 64) {              // u = A r
        float s = 0.f;
        for (int k = 0; k < 64; ++k) s += Al[t * 65 + k] * rl[k];
        ul[t] = s;
    } else if (t < 128) {      // p = S r
        const int d = t - 64;
        float s = 0.f;
        for (int k = 0; k < 64; ++k) s += Sl[d * 65 + k] * rl[k];
        pl[d] = s;
    }
    float Tr[16];
    {   // T = A @ G_b (kept in registers across the barrier)
        const int o = t >> 2, c0 = (t & 3) * 16;
        for (int ci = 0; ci < 16; ++ci) {
            const int c = c0 + ci;
            float s = 0.f;
            for (int k = 0; k < 64; ++k) s += Al[o * 65 + k] * Gl[k * 65 + c];
            Tr[ci] = s;
        }
    }
    __syncthreads();
    {   // Gl := T
        const int o = t >> 2, c0 = (t & 3) * 16;
        for (int ci = 0; ci < 16; ++ci) Gl[o * 65 + c0 + ci] = Tr[ci];
    }
    __syncthreads();
    {   // attn row-max (rank-1 terms included before max)
        const int c = t >> 2, dg = t & 3;
        float amax = -3.4e38f;
        for (int di = 0; di < 16; ++di) {
            const int d = dg * 16 + di;
            float s = 0.f;
            for (int k = 0; k < 64; ++k) s += Gl[c * 65 + k] * Sl[d * 65 + k];
            s += ul[c] * sb[d] + av[c] * pl[d] + 16384.f * av[c] * sb[d];
            amax = fmaxf(amax, s);
        }
        pm[c][dg] = amax;
    }
    __syncthreads();
    if (t < 64) aml[t] = fmaxf(fmaxf(pm[t][0], pm[t][1]), fmaxf(pm[t][2], pm[t][3]));
    __syncthreads();
    if (t < 64) {              // w_b = Wc @ attnmax
        float s = 0.f;
        for (int c = 0; c < 64; ++c) s += Wc[t * 64 + c] * aml[c];
        ws[WS_W + b * 64 + t] = s;
    }
}

// ============ K3: out[b,o,n] = w[b,o] * v[b,n] ============
__global__ __launch_bounds__(256) void k3(const float* __restrict__ ws, float* __restrict__ out) {
    __shared__ float wls[64];
    const int b = blockIdx.x >> 4, chk = blockIdx.x & 15, t = threadIdx.x;
    if (t < 64) wls[t] = ws[WS_W + b * 64 + t];
    __syncthreads();
    const size_t nb = (size_t)chk * 1024 + 4 * t;
    const float4 v4 = *(const float4*)(ws + WS_V + (size_t)b * N_ + nb);
    float* ob = out + (size_t)b * C_ * N_ + nb;
    #pragma unroll
    for (int o = 0; o < 64; ++o) {
        const float wv = wls[o];
        float4 r; r.x = wv * v4.x; r.y = wv * v4.y; r.z = wv * v4.z; r.w = wv * v4.w;
        *((float4*)(ob + (size_t)o * N_)) = r;
    }
}

extern "C" void kernel_launch(void* const* d_in, const int* in_sizes, int n_in,
                              void* d_out, int out_size, void* d_ws, size_t ws_size,
                              hipStream_t stream) {
    const float* x     = (const float*)d_in[0];
    const float* Wq    = (const float*)d_in[1];
    const float* bq    = (const float*)d_in[2];
    const float* gamma = (const float*)d_in[3];
    const float* beta  = (const float*)d_in[4];
    const float* Wq2   = (const float*)d_in[5];
    const float* bq2   = (const float*)d_in[6];
    const float* Wsr   = (const float*)d_in[7];
    const float* bsr   = (const float*)d_in[8];
    const float* Wc    = (const float*)d_in[9];
    float* ws  = (float*)d_ws;
    float* out = (float*)d_out;

    hipLaunchKernelGGL(k1,   dim3(512), dim3(256), 0, stream, x, ws);
    hipLaunchKernelGGL(k2a,  dim3(256), dim3(256), 0, stream, ws);
    hipLaunchKernelGGL(k2b1, dim3(64),  dim3(64),  0, stream, ws);
    hipLaunchKernelGGL(k2b2, dim3(1),   dim3(256), 0, stream, Wq, bq, gamma, beta, Wq2, bq2, ws);
    hipLaunchKernelGGL(k2c,  dim3(32),  dim3(256), 0, stream, Wsr, bsr, Wc, ws);
    hipLaunchKernelGGL(k3,   dim3(512), dim3(256), 0, stream, ws, out);
}

// Round 2
// 105.190 us; speedup vs baseline: 1.1775x; 1.1775x over previous
//
#include <hip/hip_runtime.h>
#include <hip/hip_bf16.h>

// Problem constants (B,C,N fixed by the reference)
#define B_ 32
#define C_ 64
#define N_ 16384
constexpr float BN_INV = 1.0f / (32.0f * 16384.0f);   // 1/(B*N)

typedef float f32x4 __attribute__((ext_vector_type(4)));
typedef short s16x8 __attribute__((ext_vector_type(8)));

// ---- workspace layout (float offsets) ----
constexpr size_t WS_GPART = 0;                               // [512][4096] per-(b,chunk) Gram partials
constexpr size_t WS_RPART = WS_GPART + (size_t)512 * 4096;   // [512][64]   rowsum partials
constexpr size_t WS_G     = WS_RPART + (size_t)512 * 64;     // [32][4096]  per-batch Gram
constexpr size_t WS_RB    = WS_G + (size_t)32 * 4096;        // [32][64]    per-batch rowsums
constexpr size_t WS_V     = WS_RB + (size_t)32 * 64;         // [32][16384] channel means
constexpr size_t WS_GBAR  = WS_V + (size_t)32 * 16384;       // [4096]      E[x x^T]
constexpr size_t WS_M     = WS_GBAR + 4096;                  // [64]        E[x]
constexpr size_t WS_A     = WS_M + 64;                       // [4096]      A = Wq2 diag(D) Wq
constexpr size_t WS_AVEC  = WS_A + 4096;                     // [64]        a vector
constexpr size_t WS_W     = WS_AVEC + 64;                    // [32][64]    w_b = Wc @ attnmax
// total ~11.2 MB of d_ws

__device__ constexpr int P1I[10] = {0,0,0,0,1,1,1,2,2,3};
__device__ constexpr int P1J[10] = {0,1,2,3,1,2,3,2,3,3};
// symmetric lookup: P1AT[a][b] = slot of upper pair (min,max)
__device__ constexpr int P1AT[4][4] = {{0,1,2,3},{1,4,5,6},{2,5,7,8},{3,6,8,9}};

__device__ __forceinline__ unsigned short bf16_rne(float f, float& hf) {
    unsigned u = __float_as_uint(f);
    unsigned r = u + 0x7FFFu + ((u >> 16) & 1u);
    hf = __uint_as_float(r & 0xFFFF0000u);
    return (unsigned short)(r >> 16);
}
__device__ __forceinline__ unsigned short bf16_rne_s(float f) {
    unsigned u = __float_as_uint(f);
    unsigned r = u + 0x7FFFu + ((u >> 16) & 1u);
    return (unsigned short)(r >> 16);
}

__device__ __forceinline__ void cvt8(const f32x4& a, const f32x4& b, s16x8& hi, s16x8& lo) {
    float f[8] = {a[0], a[1], a[2], a[3], b[0], b[1], b[2], b[3]};
    #pragma unroll
    for (int j = 0; j < 8; ++j) {
        float hf;
        unsigned short h = bf16_rne(f[j], hf);
        unsigned short l = bf16_rne_s(f[j] - hf);
        hi[j] = (short)h;
        lo[j] = (short)l;
    }
}

// ============ K1: barrier-free per-wave Gram (hi/lo bf16 MFMA) + v + rowsums ============
// Each wave independently owns 8 windows of 32 columns. Lane l loads 8 consecutive
// floats of channel 16g+(l&15) at k-slice (l>>4)*8 — exactly the MFMA A/B fragment
// layout, so no LDS staging. Cross-wave G reduction once at the end.
__global__ __launch_bounds__(256, 2) void k1(const float* __restrict__ x, float* __restrict__ ws) {
    __shared__ __align__(16) float rawb[2][26 * 256];   // 52 KB: raw acc partials, 2-buf tree
    __shared__ float rws[4][64];
    const int t = threadIdx.x, wv = t >> 6, lane = t & 63;
    const int b = blockIdx.x >> 4, ch = blockIdx.x & 15;
    const int kg = lane >> 4, cl = lane & 15;
    const float* xb = x + ((size_t)b * C_ + cl) * N_ + ch * 1024 + kg * 8;

    f32x4 accP1[10], accP2[16];
    #pragma unroll
    for (int i = 0; i < 10; ++i) accP1[i] = (f32x4){0.f, 0.f, 0.f, 0.f};
    #pragma unroll
    for (int i = 0; i < 16; ++i) accP2[i] = (f32x4){0.f, 0.f, 0.f, 0.f};
    f32x4 rs = {0.f, 0.f, 0.f, 0.f};   // rowsum partial per g-block

    f32x4 cA[4], cB[4], nA[4], nB[4];
    #pragma unroll
    for (int g = 0; g < 4; ++g) {
        cA[g] = *(const f32x4*)(xb + (size_t)g * (16 * N_) + wv * 32);
        cB[g] = *(const f32x4*)(xb + (size_t)g * (16 * N_) + wv * 32 + 4);
    }

    for (int w = 0; w < 8; ++w) {
        if (w < 7) {   // prefetch next window before any compute
            const int noff = (4 * (w + 1) + wv) * 32;
            #pragma unroll
            for (int g = 0; g < 4; ++g) {
                nA[g] = *(const f32x4*)(xb + (size_t)g * (16 * N_) + noff);
                nB[g] = *(const f32x4*)(xb + (size_t)g * (16 * N_) + noff + 4);
            }
        }
        s16x8 hi[4], lo[4];
        #pragma unroll
        for (int g = 0; g < 4; ++g) cvt8(cA[g], cB[g], hi[g], lo[g]);

        // v: sum over 64 channels = local over g + 16-lane butterfly (same cols per group)
        f32x4 s0 = cA[0] + cA[1] + cA[2] + cA[3];
        f32x4 s1 = cB[0] + cB[1] + cB[2] + cB[3];
        #pragma unroll
        for (int m = 1; m <= 8; m <<= 1) {
            #pragma unroll
            for (int j = 0; j < 4; ++j) {
                s0[j] += __shfl_xor(s0[j], m);
                s1[j] += __shfl_xor(s1[j], m);
            }
        }
        if (cl == 0) {
            float* vp = ws + WS_V + (size_t)b * N_ + ch * 1024 + (4 * w + wv) * 32 + kg * 8;
            *(f32x4*)vp       = s0 * 0.015625f;
            *(f32x4*)(vp + 4) = s1 * 0.015625f;
        }
        // rowsums (lane-local)
        #pragma unroll
        for (int g = 0; g < 4; ++g)
            rs[g] += cA[g][0] + cA[g][1] + cA[g][2] + cA[g][3]
                   + cB[g][0] + cB[g][1] + cB[g][2] + cB[g][3];

        // Gram: P1 = Hi Hi^T (10 upper blocks), P2 = Hi Lo^T (16 blocks)
        #pragma unroll
        for (int i = 0; i < 10; ++i)
            accP1[i] = __builtin_amdgcn_mfma_f32_16x16x32_bf16(hi[P1I[i]], hi[P1J[i]], accP1[i], 0, 0, 0);
        #pragma unroll
        for (int i = 0; i < 16; ++i)
            accP2[i] = __builtin_amdgcn_mfma_f32_16x16x32_bf16(hi[i >> 2], lo[i & 3], accP2[i], 0, 0, 0);

        #pragma unroll
        for (int g = 0; g < 4; ++g) { cA[g] = nA[g]; cB[g] = nB[g]; }
    }

    // rowsum: fold k-groups (lanes ^16, ^32 share channel residue)
    #pragma unroll
    for (int g = 0; g < 4; ++g) {
        rs[g] += __shfl_xor(rs[g], 16);
        rs[g] += __shfl_xor(rs[g], 32);
    }
    if (lane < 16) {
        #pragma unroll
        for (int g = 0; g < 4; ++g) rws[wv][g * 16 + lane] = rs[g];
    }

    // G reduction tree: waves 0,1 write raw; waves 2,3 add; all gather+symmetrize
    if (wv < 2) {
        float* dst = rawb[wv];
        #pragma unroll
        for (int i = 0; i < 10; ++i) *(f32x4*)(dst + i * 256 + lane * 4) = accP1[i];
        #pragma unroll
        for (int i = 0; i < 16; ++i) *(f32x4*)(dst + (10 + i) * 256 + lane * 4) = accP2[i];
    }
    __syncthreads();
    if (wv >= 2) {
        float* dst = rawb[wv & 1];
        #pragma unroll
        for (int i = 0; i < 10; ++i) {
            f32x4 o = *(f32x4*)(dst + i * 256 + lane * 4);
            *(f32x4*)(dst + i * 256 + lane * 4) = o + accP1[i];
        }
        #pragma unroll
        for (int i = 0; i < 16; ++i) {
            f32x4 o = *(f32x4*)(dst + (10 + i) * 256 + lane * 4);
            *(f32x4*)(dst + (10 + i) * 256 + lane * 4) = o + accP2[i];
        }
    }
    __syncthreads();
    if (t < 64) {
        ws[WS_RPART + (size_t)blockIdx.x * 64 + t] =
            rws[0][t] + rws[1][t] + rws[2][t] + rws[3][t];
    }
    // symmetrize-gather: G = sym(P1) + P2 + P2^T
    float* gp = ws + WS_GPART + (size_t)blockIdx.x * 4096;
    for (int e = t; e < 4096; e += 256) {
        const int r = e >> 6, c = e & 63;
        const int bi = r >> 4, bj = c >> 4, rr = r & 15, cc = c & 15;
        const int i1 = P1AT[bi][bj] * 256;
        const int o1 = (bi <= bj) ? (((rr >> 2) * 16 + cc) * 4 + (rr & 3))
                                  : (((cc >> 2) * 16 + rr) * 4 + (cc & 3));
        const int oa = ((rr >> 2) * 16 + cc) * 4 + (rr & 3);
        const int ob = ((cc >> 2) * 16 + rr) * 4 + (cc & 3);
        const int ia = (10 + bi * 4 + bj) * 256, ib = (10 + bj * 4 + bi) * 256;
        gp[e] = rawb[0][i1 + o1] + rawb[1][i1 + o1]
              + rawb[0][ia + oa] + rawb[1][ia + oa]
              + rawb[0][ib + ob] + rawb[1][ib + ob];
    }
}

// ============ K2a: reduce chunk partials -> per-batch G, r ============
__global__ __launch_bounds__(256) void k2a(float* __restrict__ ws) {
    const int b = blockIdx.x >> 3, sl = blockIdx.x & 7, t = threadIdx.x;
    #pragma unroll
    for (int h = 0; h < 2; ++h) {
        const int e = sl * 512 + h * 256 + t;
        float s = 0.f;
        for (int chn = 0; chn < 16; ++chn) s += ws[WS_GPART + ((size_t)(b * 16 + chn)) * 4096 + e];
        ws[WS_G + (size_t)b * 4096 + e] = s;
    }
    if (sl == 0 && t < 64) {
        float s = 0.f;
        for (int chn = 0; chn < 16; ++chn) s += ws[WS_RPART + (size_t)(b * 16 + chn) * 64 + t];
        ws[WS_RB + b * 64 + t] = s;
    }
}

// ============ K2b1: Gbar = E[x x^T], m = E[x] ============
__global__ __launch_bounds__(64) void k2b1(float* __restrict__ ws) {
    const int e = blockIdx.x * 64 + threadIdx.x;
    float s = 0.f;
    for (int b = 0; b < 32; ++b) s += ws[WS_G + (size_t)b * 4096 + e];
    ws[WS_GBAR + e] = s * BN_INV;
    if (blockIdx.x == 0) {
        const int c = threadIdx.x;
        float sm = 0.f;
        for (int b = 0; b < 32; ++b) sm += ws[WS_RB + b * 64 + c];
        ws[WS_M + c] = sm * BN_INV;
    }
}

// ============ K2b2: BN stats -> A = Wq2 diag(D) Wq, a vector ============
__global__ __launch_bounds__(256) void k2b2(const float* __restrict__ Wq, const float* __restrict__ bq,
                                            const float* __restrict__ gamma, const float* __restrict__ beta,
                                            const float* __restrict__ Wq2, const float* __restrict__ bq2,
                                            float* __restrict__ ws) {
    __shared__ float Gb[64 * 65], Wl[64 * 65], W2[64 * 65];
    __shared__ float mS[64], muS[64], DS[64], ab[64], qp[4][64];
    const int t = threadIdx.x;
    for (int e = t; e < 4096; e += 256) {
        const int r = e >> 6, c = e & 63;
        Gb[r * 65 + c] = ws[WS_GBAR + e];
        Wl[r * 65 + c] = Wq[e];
        W2[r * 65 + c] = Wq2[e];
    }
    if (t < 64) mS[t] = ws[WS_M + t];
    __syncthreads();
    if (t < 64) {
        float s = 0.f;
        for (int c = 0; c < 64; ++c) s += Wl[t * 65 + c] * mS[c];
        muS[t] = s;                                     // mu0 (bias-free part of mu)
    }
    __syncthreads();
    {   // quad_o = Wq_o^T Gbar Wq_o, split over 4 d-quarters (one per wave)
        const int o = t & 63, q = t >> 6;
        float s = 0.f;
        for (int dd = 0; dd < 16; ++dd) {
            const int d = q * 16 + dd;
            float inner = 0.f;
            for (int c = 0; c < 64; ++c) inner += Gb[c * 65 + d] * Wl[o * 65 + c];
            s += Wl[o * 65 + d] * inner;
        }
        qp[q][o] = s;
    }
    __syncthreads();
    if (t < 64) {
        const float quad = qp[0][t] + qp[1][t] + qp[2][t] + qp[3][t];
        const float mu0 = muS[t];
        const float var = quad - mu0 * mu0;             // bq cancels exactly
        const float D = gamma[t] * rsqrtf(var + 1e-5f);
        DS[t] = D;
        ab[t] = beta[t] - D * mu0;                      // D*(bq-mu)+beta with mu = mu0+bq
    }
    __syncthreads();
    for (int e = t; e < 4096; e += 256) {               // Gb := diag(D) Wq (Gbar now dead)
        const int k = e >> 6, c = e & 63;
        Gb[k * 65 + c] = DS[k] * Wl[k * 65 + c];
    }
    __syncthreads();
    {
        const int o = t >> 2, c0 = (t & 3) * 16;
        for (int ci = 0; ci < 16; ++ci) {
            const int c = c0 + ci;
            float s = 0.f;
            for (int k = 0; k < 64; ++k) s += W2[o * 65 + k] * Gb[k * 65 + c];
            ws[WS_A + o * 64 + c] = s;
        }
    }
    if (t < 64) {
        float s = 0.f;
        for (int k = 0; k < 64; ++k) s += W2[t * 65 + k] * ab[k];
        ws[WS_AVEC + t] = s + bq2[t];
    }
}

// ============ K2c: per-batch attn = A G S^T + rank-1 terms, rowmax, w = Wc @ max ============
__global__ __launch_bounds__(256) void k2c(const float* __restrict__ Wsr, const float* __restrict__ bsr,
                                           const float* __restrict__ Wc, float* __restrict__ ws) {
    __shared__ float Al[64 * 65], Gl[64 * 65], Sl[64 * 65];
    __shared__ float rl[64], ul[64], pl[64], av[64], sb[64], aml[64];
    __shared__ float pm[64][4];
    const int b = blockIdx.x, t = threadIdx.x;
    for (int e = t; e < 4096; e += 256) {
        const int r = e >> 6, c = e & 63;
        Al[r * 65 + c] = ws[WS_A + e];
        Gl[r * 65 + c] = ws[WS_G + (size_t)b * 4096 + e];
        Sl[r * 65 + c] = Wsr[e];
    }
    if (t < 64) { rl[t] = ws[WS_RB + b * 64 + t]; av[t] = ws[WS_AVEC + t]; sb[t] = bsr[t]; }
    __syncthreads();
    if (t < 64) {              // u = A r
        float s = 0.f;
        for (int k = 0; k < 64; ++k) s += Al[t * 65 + k] * rl[k];
        ul[t] = s;
    } else if (t < 128) {      // p = S r
        const int d = t - 64;
        float s = 0.f;
        for (int k = 0; k < 64; ++k) s += Sl[d * 65 + k] * rl[k];
        pl[d] = s;
    }
    float Tr[16];
    {   // T = A @ G_b (kept in registers across the barrier)
        const int o = t >> 2, c0 = (t & 3) * 16;
        for (int ci = 0; ci < 16; ++ci) {
            const int c = c0 + ci;
            float s = 0.f;
            for (int k = 0; k < 64; ++k) s += Al[o * 65 + k] * Gl[k * 65 + c];
            Tr[ci] = s;
        }
    }
    __syncthreads();
    {   // Gl := T
        const int o = t >> 2, c0 = (t & 3) * 16;
        for (int ci = 0; ci < 16; ++ci) Gl[o * 65 + c0 + ci] = Tr[ci];
    }
    __syncthreads();
    {   // attn row-max (rank-1 terms included before max)
        const int c = t >> 2, dg = t & 3;
        float amax = -3.4e38f;
        for (int di = 0; di < 16; ++di) {
            const int d = dg * 16 + di;
            float s = 0.f;
            for (int k = 0; k < 64; ++k) s += Gl[c * 65 + k] * Sl[d * 65 + k];
            s += ul[c] * sb[d] + av[c] * pl[d] + 16384.f * av[c] * sb[d];
            amax = fmaxf(amax, s);
        }
        pm[c][dg] = amax;
    }
    __syncthreads();
    if (t < 64) aml[t] = fmaxf(fmaxf(pm[t][0], pm[t][1]), fmaxf(pm[t][2], pm[t][3]));
    __syncthreads();
    if (t < 64) {              // w_b = Wc @ attnmax
        float s = 0.f;
        for (int c = 0; c < 64; ++c) s += Wc[t * 64 + c] * aml[c];
        ws[WS_W + b * 64 + t] = s;
    }
}

// ============ K3: out[b,o,n] = w[b,o] * v[b,n] (nontemporal, 2048 blocks) ============
__global__ __launch_bounds__(256) void k3(const float* __restrict__ ws, float* __restrict__ out) {
    const int blk = blockIdx.x;
    const int b = blk >> 6, seg = blk & 63;
    const int r0 = (seg >> 4) * 16, chk = seg & 15;
    __shared__ float wls[16];
    const int t = threadIdx.x;
    if (t < 16) wls[t] = ws[WS_W + b * 64 + r0 + t];
    __syncthreads();
    const size_t nb = (size_t)chk * 1024 + 4 * t;
    const f32x4 v4 = *(const f32x4*)(ws + WS_V + (size_t)b * N_ + nb);
    float* ob = out + ((size_t)b * C_ + r0) * N_ + nb;
    #pragma unroll
    for (int o = 0; o < 16; ++o) {
        __builtin_nontemporal_store(v4 * wls[o], (f32x4*)(ob + (size_t)o * N_));
    }
}

extern "C" void kernel_launch(void* const* d_in, const int* in_sizes, int n_in,
                              void* d_out, int out_size, void* d_ws, size_t ws_size,
                              hipStream_t stream) {
    const float* x     = (const float*)d_in[0];
    const float* Wq    = (const float*)d_in[1];
    const float* bq    = (const float*)d_in[2];
    const float* gamma = (const float*)d_in[3];
    const float* beta  = (const float*)d_in[4];
    const float* Wq2   = (const float*)d_in[5];
    const float* bq2   = (const float*)d_in[6];
    const float* Wsr   = (const float*)d_in[7];
    const float* bsr   = (const float*)d_in[8];
    const float* Wc    = (const float*)d_in[9];
    float* ws  = (float*)d_ws;
    float* out = (float*)d_out;

    hipLaunchKernelGGL(k1,   dim3(512),  dim3(256), 0, stream, x, ws);
    hipLaunchKernelGGL(k2a,  dim3(256),  dim3(256), 0, stream, ws);
    hipLaunchKernelGGL(k2b1, dim3(64),   dim3(64),  0, stream, ws);
    hipLaunchKernelGGL(k2b2, dim3(1),    dim3(256), 0, stream, Wq, bq, gamma, beta, Wq2, bq2, ws);
    hipLaunchKernelGGL(k2c,  dim3(32),   dim3(256), 0, stream, Wsr, bsr, Wc, ws);
    hipLaunchKernelGGL(k3,   dim3(2048), dim3(256), 0, stream, ws, out);
}